// Round 3
// baseline (186.186 us; speedup 1.0000x reference)
//
#include <hip/hip_runtime.h>

#define LPTS 4096
#define NTOKS 512
#define TILE 32
#define CAP (LPTS + TILE)      // compacted capacity incl. zero pad
#define GRID_B 2112            // pair blocks (grid-stride over tiles)

// ws layout (bytes):
//   float[0..3] mse_sum[4]   float[4] mask_sum
//   int[32] Lv   int[33] block-completion counter
//   OFF_GT: float4 cgt4[CAP] (gx,gy,gz,meta)  OFF_PX/PY/PZ: float4 pred coord per point (d=0..3)
//   OFF_PART: float partials[GRID_B][5]
#define OFF_GT 256
#define OFF_PX (OFF_GT + CAP * 16)
#define OFF_PY (OFF_PX + CAP * 16)
#define OFF_PZ (OFF_PY + CAP * 16)
#define OFF_PART (OFF_PZ + CAP * 16)

static __device__ __forceinline__ float nan0(float x) {
  if (!(x == x)) return 0.f;
  return fminf(fmaxf(x, -3.402823466e38f), 3.402823466e38f);
}

// sigmoid(0.5-d)+sigmoid(1-d)+sigmoid(2-d)+sigmoid(4-d) = N(e)/D(e), e=exp(delta)
static __device__ __forceinline__ float sterm(float dx, float dy, float dz, float tmp) {
  float d2 = fmaf(dx, dx, fmaf(dy, dy, dz * dz));
  float pd = sqrtf(d2);
  float delta = fminf(fabsf(pd + tmp), 25.f);
  float e = __expf(delta);
  float e2 = e * e;
  float e3 = e2 * e;
  float e4 = e2 * e2;
  float Nn = fmaf(0.0366994762f, e3, fmaf(0.7506558488f, e2, fmaf(3.3841830690f, e, 4.f)));
  float Dd = fmaf(0.00055308437f, e4,
             fmaf(0.0366994762f, e3, fmaf(0.3753279244f, e2, fmaf(1.1280610231f, e, 1.f))));
  return Nn * __builtin_amdgcn_rcpf(Dd);
}

// ---------------- Kernel A: detect + compact + MSE, one block ----------------
__global__ __launch_bounds__(1024) void prep_all_kernel(
    const float* __restrict__ XL, const float* __restrict__ Xgt,
    const void* __restrict__ crd, const void* __restrict__ dna,
    const void* __restrict__ rna, const void* __restrict__ lig,
    const void* __restrict__ tok, float* __restrict__ ws) {
  int t = threadIdx.x;
  int* wsi = (int*)ws;
  __shared__ int sflags[5];
  __shared__ int wtot[16], wbase[16];
  __shared__ int sLv;
  __shared__ float bred[16][5];
  if (t < 5) sflags[t] = 0;
  __syncthreads();
  const int* toki = (const int*)tok;
  const int* crdi = (const int*)crd;
  {
    int f0 = 0;
    for (int i = t; i < LPTS / 2; i += 1024)
      if (toki[2 * i + 1] != 0) f0 = 1;
    if (f0) atomicOr(&sflags[0], 1);
    if (t < LPTS / 4 && (unsigned)crdi[t] > 1u) atomicOr(&sflags[1], 1);
    if (t < NTOKS / 4) {
      if ((unsigned)((const int*)dna)[t] > 1u) atomicOr(&sflags[2], 1);
      if ((unsigned)((const int*)rna)[t] > 1u) atomicOr(&sflags[3], 1);
      if ((unsigned)((const int*)lig)[t] > 1u) atomicOr(&sflags[4], 1);
    }
  }
  __syncthreads();
  bool tok64 = sflags[0] == 0;
  bool crdb = sflags[1] != 0, dnab = sflags[2] != 0,
       rnab = sflags[3] != 0, ligb = sflags[4] != 0;

  // ---- load 4 consecutive points per thread (vectorized) ----
  int l0 = t * 4;
  const float4* G4 = (const float4*)Xgt;
  float4 ga = G4[3 * t], gb = G4[3 * t + 1], gc = G4[3 * t + 2];
  float gx[4] = {nan0(ga.x), nan0(ga.w), nan0(gb.z), nan0(gc.y)};
  float gy[4] = {nan0(ga.y), nan0(gb.x), nan0(gb.w), nan0(gc.z)};
  float gz[4] = {nan0(ga.z), nan0(gb.y), nan0(gc.x), nan0(gc.w)};
  const float4* X4 = (const float4*)XL;
  float xs[4][4], ys[4][4], zs[4][4];  // [d][pt]
#pragma unroll
  for (int d = 0; d < 4; ++d) {
    float4 a = X4[d * 3072 + 3 * t];
    float4 b = X4[d * 3072 + 3 * t + 1];
    float4 c = X4[d * 3072 + 3 * t + 2];
    xs[d][0] = a.x; ys[d][0] = a.y; zs[d][0] = a.z;
    xs[d][1] = a.w; ys[d][1] = b.x; zs[d][1] = b.y;
    xs[d][2] = b.z; ys[d][2] = b.w; zs[d][2] = c.x;
    xs[d][3] = c.y; ys[d][3] = c.z; zs[d][3] = c.w;
  }
  int mk[4], me[4];
  float v[5] = {0.f, 0.f, 0.f, 0.f, 0.f};
  int crdw = crdb ? crdi[t] : 0;
#pragma unroll
  for (int q = 0; q < 4; ++q) {
    int l = l0 + q;
    int tk = tok64 ? toki[2 * l] : toki[l];
    int tki = min(max(tk, 0), NTOKS - 1);
    int m  = crdb ? ((crdw >> (8 * q)) & 0xff) != 0 : crdi[l] != 0;
    int dn = (dnab ? (int)((const unsigned char*)dna)[tki] : ((const int*)dna)[tki]) != 0;
    int rn = (rnab ? (int)((const unsigned char*)rna)[tki] : ((const int*)rna)[tki]) != 0;
    int lg = (ligb ? (int)((const unsigned char*)lig)[tki] : ((const int*)lig)[tki]) != 0;
    float w = (1.f + 5.f * dn + 5.f * rn + 10.f * lg) * (float)m;
    mk[q] = m;
    me[q] = (tk & 0xFFFF) | (1 << 16) | ((dn | rn) << 17);
#pragma unroll
    for (int d = 0; d < 4; ++d) {
      float dx = xs[d][q] - gx[q], dy = ys[d][q] - gy[q], dz = zs[d][q] - gz[q];
      v[d] += w * (dx * dx + dy * dy + dz * dz);
    }
    v[4] += (float)m;
  }
  // ---- ordered block scan of per-thread counts ----
  int cnt = mk[0] + mk[1] + mk[2] + mk[3];
  int lane = t & 63, wid = t >> 6;
  int incl = cnt;
#pragma unroll
  for (int off = 1; off < 64; off <<= 1) {
    int n = __shfl_up(incl, off, 64);
    if (lane >= off) incl += n;
  }
  if (lane == 63) wtot[wid] = incl;
  __syncthreads();
  if (t == 0) {
    int run = 0;
    for (int q = 0; q < 16; ++q) { wbase[q] = run; run += wtot[q]; }
    sLv = run;
  }
  __syncthreads();
  int Lv = sLv;
  int pos = wbase[wid] + (incl - cnt);
  float4* cgt4 = (float4*)((char*)ws + OFF_GT);
  float4* cpx  = (float4*)((char*)ws + OFF_PX);
  float4* cpy  = (float4*)((char*)ws + OFF_PY);
  float4* cpz  = (float4*)((char*)ws + OFF_PZ);
#pragma unroll
  for (int q = 0; q < 4; ++q) {
    if (mk[q]) {
      cgt4[pos] = make_float4(gx[q], gy[q], gz[q], __int_as_float(me[q]));
      cpx[pos] = make_float4(xs[0][q], xs[1][q], xs[2][q], xs[3][q]);
      cpy[pos] = make_float4(ys[0][q], ys[1][q], ys[2][q], ys[3][q]);
      cpz[pos] = make_float4(zs[0][q], zs[1][q], zs[2][q], zs[3][q]);
      ++pos;
    }
  }
  if (t < TILE) {  // zero pad so partial-tile rows/cols are inert
    float4 z = make_float4(0.f, 0.f, 0.f, 0.f);
    cgt4[Lv + t] = z; cpx[Lv + t] = z; cpy[Lv + t] = z; cpz[Lv + t] = z;
  }
  // ---- MSE / mask reduction ----
#pragma unroll
  for (int k = 0; k < 5; ++k) {
    float x = v[k];
#pragma unroll
    for (int off = 32; off; off >>= 1) x += __shfl_down(x, off, 64);
    v[k] = x;
  }
  if (lane == 0)
    for (int k = 0; k < 5; ++k) bred[wid][k] = v[k];
  __syncthreads();
  if (t == 0) {
    for (int k = 0; k < 5; ++k) {
      float s = 0.f;
      for (int q = 0; q < 16; ++q) s += bred[q][k];
      ws[k] = s;
    }
    wsi[32] = Lv;
    wsi[33] = 0;  // completion counter for kernel B
  }
}

// ---------------- Kernel B: pair tiles (grid-stride) + fused final ----------------
__global__ __launch_bounds__(256) void pair_final_kernel(
    float* __restrict__ ws, const float* __restrict__ t_in, float* __restrict__ out) {
  int* wsi = (int*)ws;
  const int Lv = wsi[32];
  const int NT = (Lv + TILE - 1) >> 5;
  const int NA = NT * (NT + 1) / 2;
  const float4* cgt4 = (const float4*)((const char*)ws + OFF_GT);
  const float4* cpx  = (const float4*)((const char*)ws + OFF_PX);
  const float4* cpy  = (const float4*)((const char*)ws + OFF_PY);
  const float4* cpz  = (const float4*)((const char*)ws + OFF_PZ);
  __shared__ float4 sg[TILE], sx[TILE], sy[TILE], sz[TILE];
  __shared__ float bred[4][5];
  __shared__ int slast;
  int t = threadIdx.x;
  int r = t & 31, g = t >> 5;
  float a0 = 0.f, a1 = 0.f, a2 = 0.f, a3 = 0.f, a4 = 0.f;
  for (int b = blockIdx.x; b < NA; b += GRID_B) {
    int tj = (int)((sqrtf(8.f * (float)b + 1.f) - 1.f) * 0.5f);
    while ((tj + 1) * (tj + 2) / 2 <= b) ++tj;
    while (tj * (tj + 1) / 2 > b) --tj;
    int ti = b - tj * (tj + 1) / 2;
    int i0 = ti * TILE, j0 = tj * TILE;
    __syncthreads();  // previous tile's LDS reads complete
    if (t < 32) sg[t] = cgt4[j0 + t];
    else if (t < 64) sx[t - 32] = cpx[j0 + t - 32];
    else if (t < 96) sy[t - 64] = cpy[j0 + t - 64];
    else if (t < 128) sz[t - 96] = cpz[j0 + t - 96];
    __syncthreads();
    int i = i0 + r;
    float4 rg = cgt4[i], rx = cpx[i], ry = cpy[i], rz = cpz[i];
    int rmeta = __float_as_int(rg.w);
    int rtok = rmeta & 0xFFFF;
    bool rm = (rmeta >> 16) & 1;
    float cutoff = ((rmeta >> 17) & 1) ? 30.f : 15.f;
    bool diag = (ti == tj);
#pragma unroll
    for (int k = 0; k < 4; ++k) {
      int jj = g * 4 + k;
      float4 cg = sg[jj];
      int cmeta = __float_as_int(cg.w);
      float dgx = rg.x - cg.x, dgy = rg.y - cg.y, dgz = rg.z - cg.z;
      float gd = sqrtf(fmaf(dgx, dgx, fmaf(dgy, dgy, dgz * dgz)));
      bool pm = rm && ((cmeta >> 16) & 1) && (gd > 0.f) && (gd < cutoff) &&
                (rtok != (cmeta & 0xFFFF));
      if (diag) pm = pm && (j0 + jj > i);
      float pmf = pm ? 1.f : 0.f;
      float tmp = 1e-6f - gd;
      float4 cx = sx[jj], cy = sy[jj], cz = sz[jj];
      float s0 = sterm(rx.x - cx.x, ry.x - cy.x, rz.x - cz.x, tmp);
      float s1 = sterm(rx.y - cx.y, ry.y - cy.y, rz.y - cz.y, tmp);
      float s2 = sterm(rx.z - cx.z, ry.z - cy.z, rz.z - cz.z, tmp);
      float s3 = sterm(rx.w - cx.w, ry.w - cy.w, rz.w - cz.w, tmp);
      a0 = fmaf(s0, pmf, a0);
      a1 = fmaf(s1, pmf, a1);
      a2 = fmaf(s2, pmf, a2);
      a3 = fmaf(s3, pmf, a3);
      a4 += pmf;
    }
  }
  // one block-reduce per block
  float v[5] = {a0, a1, a2, a3, a4};
#pragma unroll
  for (int k = 0; k < 5; ++k) {
    float x = v[k];
#pragma unroll
    for (int off = 32; off; off >>= 1) x += __shfl_down(x, off, 64);
    v[k] = x;
  }
  int wid = t >> 6, lane = t & 63;
  if (lane == 0)
    for (int k = 0; k < 5; ++k) bred[wid][k] = v[k];
  __syncthreads();
  float* part = (float*)((char*)ws + OFF_PART);
  if (t == 0) {
    for (int k = 0; k < 5; ++k)
      part[blockIdx.x * 5 + k] = bred[0][k] + bred[1][k] + bred[2][k] + bred[3][k];
  }
  __threadfence();
  if (t == 0)
    slast = (atomicAdd((unsigned int*)&wsi[33], 1u) == GRID_B - 1);
  __syncthreads();
  if (slast) {
    // last block: global reduce of partials + scalar assembly
    volatile const float* vp = (volatile const float*)part;
    float u[5] = {0.f, 0.f, 0.f, 0.f, 0.f};
    for (int i = t; i < GRID_B; i += 256) {
#pragma unroll
      for (int k = 0; k < 5; ++k) u[k] += vp[i * 5 + k];
    }
#pragma unroll
    for (int k = 0; k < 5; ++k) {
      float x = u[k];
#pragma unroll
      for (int off = 32; off; off >>= 1) x += __shfl_down(x, off, 64);
      u[k] = x;
    }
    __syncthreads();
    if (lane == 0)
      for (int k = 0; k < 5; ++k) bred[wid][k] = u[k];
    __syncthreads();
    if (t == 0) {
      float ssum[4], pm_sum;
#pragma unroll
      for (int k = 0; k < 4; ++k)
        ssum[k] = bred[0][k] + bred[1][k] + bred[2][k] + bred[3][k];
      pm_sum = bred[0][4] + bred[1][4] + bred[2][4] + bred[3][4];
      float mask_sum = ws[4];
      float tot = 0.f;
#pragma unroll
      for (int d = 0; d < 4; ++d) {
        float lmse = (ws[d] * (1.f / 3.f)) / (mask_sum + 1e-4f);
        float td = t_in[d];
        float lam = (td * td + 256.f) / (256.f * td * td);
        float ldiff = fminf(lam * lmse, 2.f);
        float lddt = 0.25f * ssum[d] / (pm_sum + 1e-6f);
        tot += 0.25f * (ldiff + (1.f - lddt));
      }
      out[0] = 4.f * tot;
    }
  }
}

extern "C" void kernel_launch(void* const* d_in, const int* in_sizes, int n_in,
                              void* d_out, int out_size, void* d_ws, size_t ws_size,
                              hipStream_t stream) {
  (void)in_sizes; (void)n_in; (void)out_size; (void)ws_size;
  const float* XL  = (const float*)d_in[0];
  const float* Xgt = (const float*)d_in[1];
  float* ws = (float*)d_ws;
  float* out = (float*)d_out;
  prep_all_kernel<<<1, 1024, 0, stream>>>(XL, Xgt, d_in[2], d_in[3], d_in[4],
                                          d_in[5], d_in[6], ws);
  pair_final_kernel<<<GRID_B, 256, 0, stream>>>(ws, (const float*)d_in[7], out);
}

// Round 4
// 80.386 us; speedup vs baseline: 2.3162x; 2.3162x over previous
//
#include <hip/hip_runtime.h>

#define LPTS 4096
#define NTOKS 512
#define TILE 32
#define CAP (LPTS + TILE)      // compacted capacity incl. zero pad
#define GRID_B 2080            // pair blocks (grid-stride over tiles)
#define NBANK 16

// ws layout (floats):
//   ws[0..3] mse_sum[4]   ws[4] mask_sum        (plain stores, cross-kernel)
//   wsi[5]   Lv           wsi[6] completion ctr (atomics)
//   ws[8..87] banked lddt sums: 5 quantities x 16 banks (atomicAdd)
//   byte OFF_GT:  float4 cgt4[CAP] (gx,gy,gz,meta)
//   OFF_PX/PY/PZ: float4 per-point pred coords (lane d=0..3)
#define OFF_GT 256
#define OFF_PX (OFF_GT + CAP * 16)
#define OFF_PY (OFF_PX + CAP * 16)
#define OFF_PZ (OFF_PY + CAP * 16)

static __device__ __forceinline__ float nan0(float x) {
  if (!(x == x)) return 0.f;
  return fminf(fmaxf(x, -3.402823466e38f), 3.402823466e38f);
}

// sigmoid(0.5-d)+sigmoid(1-d)+sigmoid(2-d)+sigmoid(4-d) = N(e)/D(e), e=exp(delta)
static __device__ __forceinline__ float sterm(float dx, float dy, float dz, float tmp) {
  float d2 = fmaf(dx, dx, fmaf(dy, dy, dz * dz));
  float pd = sqrtf(d2);
  float delta = fminf(fabsf(pd + tmp), 25.f);
  float e = __expf(delta);
  float e2 = e * e;
  float e3 = e2 * e;
  float e4 = e2 * e2;
  float Nn = fmaf(0.0366994762f, e3, fmaf(0.7506558488f, e2, fmaf(3.3841830690f, e, 4.f)));
  float Dd = fmaf(0.00055308437f, e4,
             fmaf(0.0366994762f, e3, fmaf(0.3753279244f, e2, fmaf(1.1280610231f, e, 1.f))));
  return Nn * __builtin_amdgcn_rcpf(Dd);
}

// ---------------- Kernel A: detect + compact + MSE, one block ----------------
__global__ __launch_bounds__(1024) void prep_all_kernel(
    const float* __restrict__ XL, const float* __restrict__ Xgt,
    const void* __restrict__ crd, const void* __restrict__ dna,
    const void* __restrict__ rna, const void* __restrict__ lig,
    const void* __restrict__ tok, float* __restrict__ ws) {
  int t = threadIdx.x;
  int* wsi = (int*)ws;
  __shared__ int sflags[5];
  __shared__ int wtot[16], wbase[16];
  __shared__ int sLv;
  __shared__ float bred[16][5];
  if (t < 5) sflags[t] = 0;
  if (t == 6) wsi[6] = 0;                  // completion counter
  if (t >= 8 && t < 88) ws[t] = 0.f;       // banked sums
  __syncthreads();
  const int* toki = (const int*)tok;
  const int* crdi = (const int*)crd;
  {
    int f0 = 0;
    for (int i = t; i < LPTS / 2; i += 1024)
      if (toki[2 * i + 1] != 0) f0 = 1;
    if (f0) atomicOr(&sflags[0], 1);
    if (t < LPTS / 4 && (unsigned)crdi[t] > 1u) atomicOr(&sflags[1], 1);
    if (t < NTOKS / 4) {
      if ((unsigned)((const int*)dna)[t] > 1u) atomicOr(&sflags[2], 1);
      if ((unsigned)((const int*)rna)[t] > 1u) atomicOr(&sflags[3], 1);
      if ((unsigned)((const int*)lig)[t] > 1u) atomicOr(&sflags[4], 1);
    }
  }
  __syncthreads();
  bool tok64 = sflags[0] == 0;
  bool crdb = sflags[1] != 0, dnab = sflags[2] != 0,
       rnab = sflags[3] != 0, ligb = sflags[4] != 0;

  // ---- 4 consecutive points per thread, vectorized loads ----
  int l0 = t * 4;
  const float4* G4 = (const float4*)Xgt;
  float4 ga = G4[3 * t], gb = G4[3 * t + 1], gc = G4[3 * t + 2];
  float gx[4] = {nan0(ga.x), nan0(ga.w), nan0(gb.z), nan0(gc.y)};
  float gy[4] = {nan0(ga.y), nan0(gb.x), nan0(gb.w), nan0(gc.z)};
  float gz[4] = {nan0(ga.z), nan0(gb.y), nan0(gc.x), nan0(gc.w)};
  const float4* X4 = (const float4*)XL;
  float xs[4][4], ys[4][4], zs[4][4];  // [d][pt]
#pragma unroll
  for (int d = 0; d < 4; ++d) {
    float4 a = X4[d * 3072 + 3 * t];
    float4 b = X4[d * 3072 + 3 * t + 1];
    float4 c = X4[d * 3072 + 3 * t + 2];
    xs[d][0] = a.x; ys[d][0] = a.y; zs[d][0] = a.z;
    xs[d][1] = a.w; ys[d][1] = b.x; zs[d][1] = b.y;
    xs[d][2] = b.z; ys[d][2] = b.w; zs[d][2] = c.x;
    xs[d][3] = c.y; ys[d][3] = c.z; zs[d][3] = c.w;
  }
  int mk[4], me[4];
  float v[5] = {0.f, 0.f, 0.f, 0.f, 0.f};
  int crdw = crdb ? crdi[t] : 0;
#pragma unroll
  for (int q = 0; q < 4; ++q) {
    int l = l0 + q;
    int tk = tok64 ? toki[2 * l] : toki[l];
    int tki = min(max(tk, 0), NTOKS - 1);
    int m  = crdb ? ((crdw >> (8 * q)) & 0xff) != 0 : crdi[l] != 0;
    int dn = (dnab ? (int)((const unsigned char*)dna)[tki] : ((const int*)dna)[tki]) != 0;
    int rn = (rnab ? (int)((const unsigned char*)rna)[tki] : ((const int*)rna)[tki]) != 0;
    int lg = (ligb ? (int)((const unsigned char*)lig)[tki] : ((const int*)lig)[tki]) != 0;
    float w = (1.f + 5.f * dn + 5.f * rn + 10.f * lg) * (float)m;
    mk[q] = m;
    me[q] = (tk & 0xFFFF) | (1 << 16) | ((dn | rn) << 17);
#pragma unroll
    for (int d = 0; d < 4; ++d) {
      float dx = xs[d][q] - gx[q], dy = ys[d][q] - gy[q], dz = zs[d][q] - gz[q];
      v[d] += w * (dx * dx + dy * dy + dz * dz);
    }
    v[4] += (float)m;
  }
  // ---- ordered block scan ----
  int cnt = mk[0] + mk[1] + mk[2] + mk[3];
  int lane = t & 63, wid = t >> 6;
  int incl = cnt;
#pragma unroll
  for (int off = 1; off < 64; off <<= 1) {
    int n = __shfl_up(incl, off, 64);
    if (lane >= off) incl += n;
  }
  if (lane == 63) wtot[wid] = incl;
  __syncthreads();
  if (t == 0) {
    int run = 0;
    for (int q = 0; q < 16; ++q) { wbase[q] = run; run += wtot[q]; }
    sLv = run;
  }
  __syncthreads();
  int Lv = sLv;
  int pos = wbase[wid] + (incl - cnt);
  float4* cgt4 = (float4*)((char*)ws + OFF_GT);
  float4* cpx  = (float4*)((char*)ws + OFF_PX);
  float4* cpy  = (float4*)((char*)ws + OFF_PY);
  float4* cpz  = (float4*)((char*)ws + OFF_PZ);
#pragma unroll
  for (int q = 0; q < 4; ++q) {
    if (mk[q]) {
      cgt4[pos] = make_float4(gx[q], gy[q], gz[q], __int_as_float(me[q]));
      cpx[pos] = make_float4(xs[0][q], xs[1][q], xs[2][q], xs[3][q]);
      cpy[pos] = make_float4(ys[0][q], ys[1][q], ys[2][q], ys[3][q]);
      cpz[pos] = make_float4(zs[0][q], zs[1][q], zs[2][q], zs[3][q]);
      ++pos;
    }
  }
  if (t < TILE) {  // zero pad so partial tiles are inert
    float4 z = make_float4(0.f, 0.f, 0.f, 0.f);
    cgt4[Lv + t] = z; cpx[Lv + t] = z; cpy[Lv + t] = z; cpz[Lv + t] = z;
  }
  // ---- MSE / mask reduction ----
#pragma unroll
  for (int k = 0; k < 5; ++k) {
    float x = v[k];
#pragma unroll
    for (int off = 32; off; off >>= 1) x += __shfl_down(x, off, 64);
    v[k] = x;
  }
  if (lane == 0)
    for (int k = 0; k < 5; ++k) bred[wid][k] = v[k];
  __syncthreads();
  if (t == 0) {
    for (int k = 0; k < 5; ++k) {
      float s = 0.f;
      for (int q = 0; q < 16; ++q) s += bred[q][k];
      ws[k] = s;
    }
    wsi[5] = Lv;
  }
}

// ------- Kernel B: pair tiles (grid-stride) + fenceless atomic final -------
__global__ __launch_bounds__(256) void pair_final_kernel(
    float* __restrict__ ws, const float* __restrict__ t_in, float* __restrict__ out) {
  int* wsi = (int*)ws;
  const int Lv = wsi[5];
  const int NT = (Lv + TILE - 1) >> 5;
  const int NA = NT * (NT + 1) / 2;
  const float4* cgt4 = (const float4*)((const char*)ws + OFF_GT);
  const float4* cpx  = (const float4*)((const char*)ws + OFF_PX);
  const float4* cpy  = (const float4*)((const char*)ws + OFF_PY);
  const float4* cpz  = (const float4*)((const char*)ws + OFF_PZ);
  __shared__ float4 sg[TILE], sx[TILE], sy[TILE], sz[TILE];
  __shared__ float bred[4][5];
  __shared__ int slast;
  int t = threadIdx.x;
  int r = t & 31, g = t >> 5;
  float a0 = 0.f, a1 = 0.f, a2 = 0.f, a3 = 0.f, a4 = 0.f;
  for (int b = blockIdx.x; b < NA; b += GRID_B) {
    int tj = (int)((sqrtf(8.f * (float)b + 1.f) - 1.f) * 0.5f);
    while ((tj + 1) * (tj + 2) / 2 <= b) ++tj;
    while (tj * (tj + 1) / 2 > b) --tj;
    int ti = b - tj * (tj + 1) / 2;
    int i0 = ti * TILE, j0 = tj * TILE;
    __syncthreads();
    if (t < 32) sg[t] = cgt4[j0 + t];
    else if (t < 64) sx[t - 32] = cpx[j0 + t - 32];
    else if (t < 96) sy[t - 64] = cpy[j0 + t - 64];
    else if (t < 128) sz[t - 96] = cpz[j0 + t - 96];
    __syncthreads();
    int i = i0 + r;
    float4 rg = cgt4[i], rx = cpx[i], ry = cpy[i], rz = cpz[i];
    int rmeta = __float_as_int(rg.w);
    int rtok = rmeta & 0xFFFF;
    bool rm = (rmeta >> 16) & 1;
    float cutoff = ((rmeta >> 17) & 1) ? 30.f : 15.f;
    bool diag = (ti == tj);
#pragma unroll
    for (int k = 0; k < 4; ++k) {
      int jj = g * 4 + k;
      float4 cg = sg[jj];
      int cmeta = __float_as_int(cg.w);
      float dgx = rg.x - cg.x, dgy = rg.y - cg.y, dgz = rg.z - cg.z;
      float gd = sqrtf(fmaf(dgx, dgx, fmaf(dgy, dgy, dgz * dgz)));
      bool pm = rm && ((cmeta >> 16) & 1) && (gd > 0.f) && (gd < cutoff) &&
                (rtok != (cmeta & 0xFFFF));
      if (diag) pm = pm && (j0 + jj > i);
      float pmf = pm ? 1.f : 0.f;
      float tmp = 1e-6f - gd;
      float4 cx = sx[jj], cy = sy[jj], cz = sz[jj];
      float s0 = sterm(rx.x - cx.x, ry.x - cy.x, rz.x - cz.x, tmp);
      float s1 = sterm(rx.y - cx.y, ry.y - cy.y, rz.y - cz.y, tmp);
      float s2 = sterm(rx.z - cx.z, ry.z - cy.z, rz.z - cz.z, tmp);
      float s3 = sterm(rx.w - cx.w, ry.w - cy.w, rz.w - cz.w, tmp);
      a0 = fmaf(s0, pmf, a0);
      a1 = fmaf(s1, pmf, a1);
      a2 = fmaf(s2, pmf, a2);
      a3 = fmaf(s3, pmf, a3);
      a4 += pmf;
    }
  }
  // block reduce
  float v[5] = {a0, a1, a2, a3, a4};
#pragma unroll
  for (int k = 0; k < 5; ++k) {
    float x = v[k];
#pragma unroll
    for (int off = 32; off; off >>= 1) x += __shfl_down(x, off, 64);
    v[k] = x;
  }
  int wid = t >> 6, lane = t & 63;
  if (lane == 0)
    for (int k = 0; k < 5; ++k) bred[wid][k] = v[k];
  __syncthreads();
  if (t == 0) {
    int bank = blockIdx.x & (NBANK - 1);
    float s[5];
#pragma unroll
    for (int k = 0; k < 5; ++k) {
      s[k] = bred[0][k] + bred[1][k] + bred[2][k] + bred[3][k];
      atomicAdd(&ws[8 + k * NBANK + bank], s[k]);   // device-scope, coherent point
    }
    // hand-rolled release: wait until our atomics retired at coherent point
    asm volatile("s_waitcnt vmcnt(0)" ::: "memory");
    unsigned old = atomicAdd((unsigned*)&wsi[6], 1u);
    slast = (old == (unsigned)(GRID_B - 1));
  }
  __syncthreads();
  if (slast) {
    __shared__ float sfin[5 * NBANK];
    if (t < 5 * NBANK)
      sfin[t] = __hip_atomic_load(&ws[8 + t], __ATOMIC_RELAXED,
                                  __HIP_MEMORY_SCOPE_AGENT);
    __syncthreads();
    if (t == 0) {
      float ssum[5];
#pragma unroll
      for (int k = 0; k < 5; ++k) {
        float x = 0.f;
        for (int q = 0; q < NBANK; ++q) x += sfin[k * NBANK + q];
        ssum[k] = x;
      }
      float mask_sum = ws[4];
      float pm_sum = ssum[4];
      float tot = 0.f;
#pragma unroll
      for (int d = 0; d < 4; ++d) {
        float lmse = (ws[d] * (1.f / 3.f)) / (mask_sum + 1e-4f);
        float td = t_in[d];
        float lam = (td * td + 256.f) / (256.f * td * td);
        float ldiff = fminf(lam * lmse, 2.f);
        float lddt = 0.25f * ssum[d] / (pm_sum + 1e-6f);
        tot += 0.25f * (ldiff + (1.f - lddt));
      }
      out[0] = 4.f * tot;
    }
  }
}

extern "C" void kernel_launch(void* const* d_in, const int* in_sizes, int n_in,
                              void* d_out, int out_size, void* d_ws, size_t ws_size,
                              hipStream_t stream) {
  (void)in_sizes; (void)n_in; (void)out_size; (void)ws_size;
  const float* XL  = (const float*)d_in[0];
  const float* Xgt = (const float*)d_in[1];
  float* ws = (float*)d_ws;
  float* out = (float*)d_out;
  prep_all_kernel<<<1, 1024, 0, stream>>>(XL, Xgt, d_in[2], d_in[3], d_in[4],
                                          d_in[5], d_in[6], ws);
  pair_final_kernel<<<GRID_B, 256, 0, stream>>>(ws, (const float*)d_in[7], out);
}

// Round 5
// 33.080 us; speedup vs baseline: 5.6284x; 2.4301x over previous
//
#include <hip/hip_runtime.h>

#define LPTS 4096
#define NTOKS 512
#define TILE 32
#define CAP (LPTS + TILE)      // compacted capacity incl. zero pad
#define GRID_B 2080            // pair blocks (grid-stride over tiles)

// ws layout:
//   ws[0..3] mse_sum[4]   ws[4] mask_sum   wsi[5] Lv      (plain, cross-kernel)
//   byte OFF_GT:  float4 cgt4[CAP] (gx,gy,gz,meta)
//   OFF_PX/PY/PZ: float4 per-point pred coords (lane d=0..3)
//   OFF_PART:     float partials[GRID_B][5]
#define OFF_GT 256
#define OFF_PX (OFF_GT + CAP * 16)
#define OFF_PY (OFF_PX + CAP * 16)
#define OFF_PZ (OFF_PY + CAP * 16)
#define OFF_PART (OFF_PZ + CAP * 16)

static __device__ __forceinline__ float nan0(float x) {
  if (!(x == x)) return 0.f;
  return fminf(fmaxf(x, -3.402823466e38f), 3.402823466e38f);
}

// sigmoid(0.5-d)+sigmoid(1-d)+sigmoid(2-d)+sigmoid(4-d) = N(e)/D(e), e=exp(delta)
static __device__ __forceinline__ float sterm(float dx, float dy, float dz, float tmp) {
  float d2 = fmaf(dx, dx, fmaf(dy, dy, dz * dz));
  float pd = sqrtf(d2);
  float delta = fminf(fabsf(pd + tmp), 25.f);
  float e = __expf(delta);
  float e2 = e * e;
  float e3 = e2 * e;
  float e4 = e2 * e2;
  float Nn = fmaf(0.0366994762f, e3, fmaf(0.7506558488f, e2, fmaf(3.3841830690f, e, 4.f)));
  float Dd = fmaf(0.00055308437f, e4,
             fmaf(0.0366994762f, e3, fmaf(0.3753279244f, e2, fmaf(1.1280610231f, e, 1.f))));
  return Nn * __builtin_amdgcn_rcpf(Dd);
}

// ---------------- Kernel A: detect + compact + MSE, one block ----------------
__global__ __launch_bounds__(1024) void prep_all_kernel(
    const float* __restrict__ XL, const float* __restrict__ Xgt,
    const void* __restrict__ crd, const void* __restrict__ dna,
    const void* __restrict__ rna, const void* __restrict__ lig,
    const void* __restrict__ tok, float* __restrict__ ws) {
  int t = threadIdx.x;
  int* wsi = (int*)ws;
  __shared__ int sflags[5];
  __shared__ int wtot[16], wbase[16];
  __shared__ int sLv;
  __shared__ float bred[16][5];
  if (t < 5) sflags[t] = 0;
  __syncthreads();
  const int* toki = (const int*)tok;
  const int* crdi = (const int*)crd;
  {
    int f0 = 0;
    for (int i = t; i < LPTS / 2; i += 1024)
      if (toki[2 * i + 1] != 0) f0 = 1;
    if (f0) atomicOr(&sflags[0], 1);
    if (t < LPTS / 4 && (unsigned)crdi[t] > 1u) atomicOr(&sflags[1], 1);
    if (t < NTOKS / 4) {
      if ((unsigned)((const int*)dna)[t] > 1u) atomicOr(&sflags[2], 1);
      if ((unsigned)((const int*)rna)[t] > 1u) atomicOr(&sflags[3], 1);
      if ((unsigned)((const int*)lig)[t] > 1u) atomicOr(&sflags[4], 1);
    }
  }
  __syncthreads();
  bool tok64 = sflags[0] == 0;
  bool crdb = sflags[1] != 0, dnab = sflags[2] != 0,
       rnab = sflags[3] != 0, ligb = sflags[4] != 0;

  // ---- 4 consecutive points per thread, vectorized loads ----
  int l0 = t * 4;
  const float4* G4 = (const float4*)Xgt;
  float4 ga = G4[3 * t], gb = G4[3 * t + 1], gc = G4[3 * t + 2];
  float gx[4] = {nan0(ga.x), nan0(ga.w), nan0(gb.z), nan0(gc.y)};
  float gy[4] = {nan0(ga.y), nan0(gb.x), nan0(gb.w), nan0(gc.z)};
  float gz[4] = {nan0(ga.z), nan0(gb.y), nan0(gc.x), nan0(gc.w)};
  const float4* X4 = (const float4*)XL;
  float xs[4][4], ys[4][4], zs[4][4];  // [d][pt]
#pragma unroll
  for (int d = 0; d < 4; ++d) {
    float4 a = X4[d * 3072 + 3 * t];
    float4 b = X4[d * 3072 + 3 * t + 1];
    float4 c = X4[d * 3072 + 3 * t + 2];
    xs[d][0] = a.x; ys[d][0] = a.y; zs[d][0] = a.z;
    xs[d][1] = a.w; ys[d][1] = b.x; zs[d][1] = b.y;
    xs[d][2] = b.z; ys[d][2] = b.w; zs[d][2] = c.x;
    xs[d][3] = c.y; ys[d][3] = c.z; zs[d][3] = c.w;
  }
  int mk[4], me[4];
  float v[5] = {0.f, 0.f, 0.f, 0.f, 0.f};
  int crdw = crdb ? crdi[t] : 0;
#pragma unroll
  for (int q = 0; q < 4; ++q) {
    int l = l0 + q;
    int tk = tok64 ? toki[2 * l] : toki[l];
    int tki = min(max(tk, 0), NTOKS - 1);
    int m  = crdb ? ((crdw >> (8 * q)) & 0xff) != 0 : crdi[l] != 0;
    int dn = (dnab ? (int)((const unsigned char*)dna)[tki] : ((const int*)dna)[tki]) != 0;
    int rn = (rnab ? (int)((const unsigned char*)rna)[tki] : ((const int*)rna)[tki]) != 0;
    int lg = (ligb ? (int)((const unsigned char*)lig)[tki] : ((const int*)lig)[tki]) != 0;
    float w = (1.f + 5.f * dn + 5.f * rn + 10.f * lg) * (float)m;
    mk[q] = m;
    me[q] = (tk & 0xFFFF) | (1 << 16) | ((dn | rn) << 17);
#pragma unroll
    for (int d = 0; d < 4; ++d) {
      float dx = xs[d][q] - gx[q], dy = ys[d][q] - gy[q], dz = zs[d][q] - gz[q];
      v[d] += w * (dx * dx + dy * dy + dz * dz);
    }
    v[4] += (float)m;
  }
  // ---- ordered block scan ----
  int cnt = mk[0] + mk[1] + mk[2] + mk[3];
  int lane = t & 63, wid = t >> 6;
  int incl = cnt;
#pragma unroll
  for (int off = 1; off < 64; off <<= 1) {
    int n = __shfl_up(incl, off, 64);
    if (lane >= off) incl += n;
  }
  if (lane == 63) wtot[wid] = incl;
  __syncthreads();
  if (t == 0) {
    int run = 0;
    for (int q = 0; q < 16; ++q) { wbase[q] = run; run += wtot[q]; }
    sLv = run;
  }
  __syncthreads();
  int Lv = sLv;
  int pos = wbase[wid] + (incl - cnt);
  float4* cgt4 = (float4*)((char*)ws + OFF_GT);
  float4* cpx  = (float4*)((char*)ws + OFF_PX);
  float4* cpy  = (float4*)((char*)ws + OFF_PY);
  float4* cpz  = (float4*)((char*)ws + OFF_PZ);
#pragma unroll
  for (int q = 0; q < 4; ++q) {
    if (mk[q]) {
      cgt4[pos] = make_float4(gx[q], gy[q], gz[q], __int_as_float(me[q]));
      cpx[pos] = make_float4(xs[0][q], xs[1][q], xs[2][q], xs[3][q]);
      cpy[pos] = make_float4(ys[0][q], ys[1][q], ys[2][q], ys[3][q]);
      cpz[pos] = make_float4(zs[0][q], zs[1][q], zs[2][q], zs[3][q]);
      ++pos;
    }
  }
  if (t < TILE) {  // zero pad so partial tiles are inert
    float4 z = make_float4(0.f, 0.f, 0.f, 0.f);
    cgt4[Lv + t] = z; cpx[Lv + t] = z; cpy[Lv + t] = z; cpz[Lv + t] = z;
  }
  // ---- MSE / mask reduction ----
#pragma unroll
  for (int k = 0; k < 5; ++k) {
    float x = v[k];
#pragma unroll
    for (int off = 32; off; off >>= 1) x += __shfl_down(x, off, 64);
    v[k] = x;
  }
  if (lane == 0)
    for (int k = 0; k < 5; ++k) bred[wid][k] = v[k];
  __syncthreads();
  if (t == 0) {
    for (int k = 0; k < 5; ++k) {
      float s = 0.f;
      for (int q = 0; q < 16; ++q) s += bred[q][k];
      ws[k] = s;
    }
    wsi[5] = Lv;
  }
}

// ---------- Kernel B: pair tiles, pure compute + one plain store ----------
__global__ __launch_bounds__(256) void pair_kernel(float* __restrict__ ws) {
  const int* wsi = (const int*)ws;
  const int Lv = wsi[5];
  const int NT = (Lv + TILE - 1) >> 5;
  const int NA = NT * (NT + 1) / 2;
  const float4* cgt4 = (const float4*)((const char*)ws + OFF_GT);
  const float4* cpx  = (const float4*)((const char*)ws + OFF_PX);
  const float4* cpy  = (const float4*)((const char*)ws + OFF_PY);
  const float4* cpz  = (const float4*)((const char*)ws + OFF_PZ);
  __shared__ float4 sg[TILE], sx[TILE], sy[TILE], sz[TILE];
  __shared__ float bred[4][5];
  int t = threadIdx.x;
  int r = t & 31, g = t >> 5;
  float a0 = 0.f, a1 = 0.f, a2 = 0.f, a3 = 0.f, a4 = 0.f;
  for (int b = blockIdx.x; b < NA; b += GRID_B) {
    int tj = (int)((sqrtf(8.f * (float)b + 1.f) - 1.f) * 0.5f);
    while ((tj + 1) * (tj + 2) / 2 <= b) ++tj;
    while (tj * (tj + 1) / 2 > b) --tj;
    int ti = b - tj * (tj + 1) / 2;
    int i0 = ti * TILE, j0 = tj * TILE;
    __syncthreads();
    if (t < 32) sg[t] = cgt4[j0 + t];
    else if (t < 64) sx[t - 32] = cpx[j0 + t - 32];
    else if (t < 96) sy[t - 64] = cpy[j0 + t - 64];
    else if (t < 128) sz[t - 96] = cpz[j0 + t - 96];
    __syncthreads();
    int i = i0 + r;
    float4 rg = cgt4[i], rx = cpx[i], ry = cpy[i], rz = cpz[i];
    int rmeta = __float_as_int(rg.w);
    int rtok = rmeta & 0xFFFF;
    bool rm = (rmeta >> 16) & 1;
    float cutoff = ((rmeta >> 17) & 1) ? 30.f : 15.f;
    bool diag = (ti == tj);
#pragma unroll
    for (int k = 0; k < 4; ++k) {
      int jj = g * 4 + k;
      float4 cg = sg[jj];
      int cmeta = __float_as_int(cg.w);
      float dgx = rg.x - cg.x, dgy = rg.y - cg.y, dgz = rg.z - cg.z;
      float gd = sqrtf(fmaf(dgx, dgx, fmaf(dgy, dgy, dgz * dgz)));
      bool pm = rm && ((cmeta >> 16) & 1) && (gd > 0.f) && (gd < cutoff) &&
                (rtok != (cmeta & 0xFFFF));
      if (diag) pm = pm && (j0 + jj > i);
      float pmf = pm ? 1.f : 0.f;
      float tmp = 1e-6f - gd;
      float4 cx = sx[jj], cy = sy[jj], cz = sz[jj];
      float s0 = sterm(rx.x - cx.x, ry.x - cy.x, rz.x - cz.x, tmp);
      float s1 = sterm(rx.y - cx.y, ry.y - cy.y, rz.y - cz.y, tmp);
      float s2 = sterm(rx.z - cx.z, ry.z - cy.z, rz.z - cz.z, tmp);
      float s3 = sterm(rx.w - cx.w, ry.w - cy.w, rz.w - cz.w, tmp);
      a0 = fmaf(s0, pmf, a0);
      a1 = fmaf(s1, pmf, a1);
      a2 = fmaf(s2, pmf, a2);
      a3 = fmaf(s3, pmf, a3);
      a4 += pmf;
    }
  }
  // block reduce -> one plain store (kernel boundary = release)
  float v[5] = {a0, a1, a2, a3, a4};
#pragma unroll
  for (int k = 0; k < 5; ++k) {
    float x = v[k];
#pragma unroll
    for (int off = 32; off; off >>= 1) x += __shfl_down(x, off, 64);
    v[k] = x;
  }
  int wid = t >> 6, lane = t & 63;
  if (lane == 0)
    for (int k = 0; k < 5; ++k) bred[wid][k] = v[k];
  __syncthreads();
  if (t == 0) {
    float* part = (float*)((char*)ws + OFF_PART);
#pragma unroll
    for (int k = 0; k < 5; ++k)
      part[blockIdx.x * 5 + k] = bred[0][k] + bred[1][k] + bred[2][k] + bred[3][k];
  }
}

// ---------------- Kernel C: final reduce + scalar assembly ----------------
__global__ __launch_bounds__(256) void final_kernel(
    const float* __restrict__ ws, const float* __restrict__ t_in,
    float* __restrict__ out) {
  int t = threadIdx.x;
  const float* part = (const float*)((const char*)ws + OFF_PART);
  float u[5] = {0.f, 0.f, 0.f, 0.f, 0.f};
  for (int i = t; i < GRID_B; i += 256) {
#pragma unroll
    for (int k = 0; k < 5; ++k) u[k] += part[i * 5 + k];
  }
#pragma unroll
  for (int k = 0; k < 5; ++k) {
    float x = u[k];
#pragma unroll
    for (int off = 32; off; off >>= 1) x += __shfl_down(x, off, 64);
    u[k] = x;
  }
  __shared__ float bred[4][5];
  int wid = t >> 6, lane = t & 63;
  if (lane == 0)
    for (int k = 0; k < 5; ++k) bred[wid][k] = u[k];
  __syncthreads();
  if (t == 0) {
    float ssum[5];
#pragma unroll
    for (int k = 0; k < 5; ++k)
      ssum[k] = bred[0][k] + bred[1][k] + bred[2][k] + bred[3][k];
    float mask_sum = ws[4];
    float pm_sum = ssum[4];
    float tot = 0.f;
#pragma unroll
    for (int d = 0; d < 4; ++d) {
      float lmse = (ws[d] * (1.f / 3.f)) / (mask_sum + 1e-4f);
      float td = t_in[d];
      float lam = (td * td + 256.f) / (256.f * td * td);
      float ldiff = fminf(lam * lmse, 2.f);
      float lddt = 0.25f * ssum[d] / (pm_sum + 1e-6f);
      tot += 0.25f * (ldiff + (1.f - lddt));
    }
    out[0] = 4.f * tot;
  }
}

extern "C" void kernel_launch(void* const* d_in, const int* in_sizes, int n_in,
                              void* d_out, int out_size, void* d_ws, size_t ws_size,
                              hipStream_t stream) {
  (void)in_sizes; (void)n_in; (void)out_size; (void)ws_size;
  const float* XL  = (const float*)d_in[0];
  const float* Xgt = (const float*)d_in[1];
  float* ws = (float*)d_ws;
  float* out = (float*)d_out;
  prep_all_kernel<<<1, 1024, 0, stream>>>(XL, Xgt, d_in[2], d_in[3], d_in[4],
                                          d_in[5], d_in[6], ws);
  pair_kernel<<<GRID_B, 256, 0, stream>>>(ws);
  final_kernel<<<1, 256, 0, stream>>>(ws, (const float*)d_in[7], out);
}